// Round 3
// baseline (9918.893 us; speedup 1.0000x reference)
//
#include <hip/hip_runtime.h>
#include <cmath>

#define B_ 64
#define T_ 512
#define I_ 1024
#define H_ 1024

// ---------------------------------------------------------------------------
// Kernel 1: xw[m, n] = sum_k x[m,k] * W[n,k] + bW[n]   (M=32768, N=1024, K=1024)
// Written into the out1 region of d_out. 128x128 tile, BK=8, 8x8 per thread.
// (unchanged from verified baseline)
// ---------------------------------------------------------------------------
#define TS 128
#define KS 8

__global__ __launch_bounds__(256) void gemm_xw(const float* __restrict__ x,
                                               const float* __restrict__ W,
                                               const float* __restrict__ bW,
                                               float* __restrict__ out) {
    __shared__ float As[KS][TS];
    __shared__ float Bs[KS][TS];

    const int tid = threadIdx.x;
    const int tx = tid & 15;
    const int ty = tid >> 4;
    const int m0 = blockIdx.y * TS;
    const int n0 = blockIdx.x * TS;

    const int lr = tid >> 1;
    const int lk = (tid & 1) * 4;

    const float* xa = x + (size_t)(m0 + lr) * I_ + lk;
    const float* wb = W + (size_t)(n0 + lr) * I_ + lk;

    float acc[8][8] = {};

    for (int k0 = 0; k0 < I_; k0 += KS) {
        float4 a = *(const float4*)(xa + k0);
        float4 bv = *(const float4*)(wb + k0);
        __syncthreads();
        As[lk + 0][lr] = a.x;  As[lk + 1][lr] = a.y;
        As[lk + 2][lr] = a.z;  As[lk + 3][lr] = a.w;
        Bs[lk + 0][lr] = bv.x; Bs[lk + 1][lr] = bv.y;
        Bs[lk + 2][lr] = bv.z; Bs[lk + 3][lr] = bv.w;
        __syncthreads();
#pragma unroll
        for (int kk = 0; kk < KS; ++kk) {
            float av[8], bw8[8];
            *(float4*)&av[0]  = *(const float4*)&As[kk][ty * 8];
            *(float4*)&av[4]  = *(const float4*)&As[kk][ty * 8 + 4];
            *(float4*)&bw8[0] = *(const float4*)&Bs[kk][tx * 8];
            *(float4*)&bw8[4] = *(const float4*)&Bs[kk][tx * 8 + 4];
#pragma unroll
            for (int i = 0; i < 8; ++i)
#pragma unroll
                for (int j = 0; j < 8; ++j)
                    acc[i][j] += av[i] * bw8[j];
        }
    }

    float bias[8];
    *(float4*)&bias[0] = *(const float4*)&bW[n0 + tx * 8];
    *(float4*)&bias[4] = *(const float4*)&bW[n0 + tx * 8 + 4];
#pragma unroll
    for (int i = 0; i < 8; ++i) {
        float* o = out + (size_t)(m0 + ty * 8 + i) * H_ + n0 + tx * 8;
        float4 v0, v1;
        v0.x = acc[i][0] + bias[0]; v0.y = acc[i][1] + bias[1];
        v0.z = acc[i][2] + bias[2]; v0.w = acc[i][3] + bias[3];
        v1.x = acc[i][4] + bias[4]; v1.y = acc[i][5] + bias[5];
        v1.z = acc[i][6] + bias[6]; v1.w = acc[i][7] + bias[7];
        *(float4*)(o)     = v0;
        *(float4*)(o + 4) = v1;
    }
}

// ---------------------------------------------------------------------------
// Kernel 2: persistent recurrence, batch-grouped, LDS-staged h3.
// 256 WGs x 256 threads. WG g: p = g&7 (batches 8p..8p+8), q = g>>3
// (cols 32q..32q+32). U slice (32x1024, rotation-swizzled) + h3 slice
// (8x1024) resident in LDS = exactly 160 KiB.
//
// Per step: group-local flag barrier (32 flags; RELEASE store / ACQUIRE
// spin so h3 data can never lag its flag at the coherence point); then
// each WG stages its 32 KB h3 slice global->LDS ONCE (atomic agent
// loads), and the GEMV runs entirely from LDS (global h3 traffic
// 64 MB/step -> 8 MB/step vs r1).
//
// GEMV arithmetic is ORDER-IDENTICAL to the verified r1 kernel (float2
// granule, k = m*32 + 2kq + {0,1}, m = 0..31 ascending, same accumulate
// expression, same shfl_xor butterfly) -> per-(b,h) results bit-match r1
// (recurrence is drift-sensitive; do not reassociate the k-sum).
//
// Thread map: tile = tid>>4 (bt = tile&1 batch-half, ct = tile>>1 col),
// kq = tid&15. bt varies INSIDE a wave -> U reads are 2-way broadcast.
// U rotation Ul[r][(k+4r)&1023] kills the row-stride bank aliasing.
// Owner: b = 8p + 4bt + (kq>>2), h = 32q + ct + 8*(kq&3)  (bijective).
// ---------------------------------------------------------------------------
typedef unsigned long long ull;

__device__ __forceinline__ ull aload(const ull* p) {
    return __hip_atomic_load(p, __ATOMIC_RELAXED, __HIP_MEMORY_SCOPE_AGENT);
}

__global__ __launch_bounds__(256) void rnn_scan(const float* __restrict__ U,
                                                const float* __restrict__ bU,
                                                float* __restrict__ out,
                                                float* __restrict__ hx0,
                                                float* __restrict__ hx1,
                                                unsigned* __restrict__ flags) {
    __shared__ __align__(16) float Ul[32][1024];   // 131072 B (rot-swizzled)
    __shared__ __align__(16) float Hl[8][1024];    //  32768 B

    const int g = blockIdx.x;
    const int p = g & 7;          // batch group
    const int q = g >> 3;         // col group
    const int tid = threadIdx.x;

    const int tile = tid >> 4;    // 0..15
    const int kq = tid & 15;      // 0..15
    const int bt = tile & 1;      // batch half (varies within wave)
    const int ct = tile >> 1;     // 0..7 col index

    // owner identity: bijective over tid
    const int b = p * 8 + bt * 4 + (kq >> 2);
    const int h = q * 32 + ct + 8 * (kq & 3);

    // --- stage U rows [32q, 32q+32) into LDS, rotation swizzle ---
    // U[q*32+r][k]  ->  Ul[r][(k + 4r) & 1023]
    {
        const float* Ubase = U + (size_t)q * 32 * H_;
#pragma unroll 4
        for (int it = 0; it < 32; ++it) {
            int f4 = it * 256 + tid;        // float4 index, coalesced
            int r = f4 >> 8;                // 256 float4 per row
            int k = (f4 & 255) * 4;
            float4 v = *(const float4*)(Ubase + (size_t)r * H_ + k);
            int kd = (k + 4 * r) & 1023;
            *(float4*)&Ul[r][kd] = v;
        }
    }
    __syncthreads();

    const float bUh = bU[h];
    float s = 0.0f;
    float* out2 = out + (size_t)B_ * T_ * H_;

    const int lb0 = bt * 4;                 // local batch base in Hl
    // per-thread U row indices + rotated base offsets (k = m*32 + 2kq)
    int rowc[4], uo[4];
#pragma unroll
    for (int c = 0; c < 4; ++c) {
        rowc[c] = ct + 8 * c;
        uo[c] = (4 * rowc[c] + 2 * kq) & 1023;
    }
    const int hbase = 2 * kq;

    float xwv = out[(size_t)b * T_ * H_ + h];   // xw for t=0

    for (int t = 0; t < T_; ++t) {
        // (a) elementwise: h3 = tanh(xw + s); out1 in place
        const size_t rowoff = ((size_t)b * T_ + t) * H_;
        float h3 = tanhf(xwv + s);
        out[rowoff + h] = h3;
        if (t == T_ - 1) {
            out2[(size_t)b * H_ + h] = h3;
            break;
        }

        float* hx = (t & 1) ? hx1 : hx0;
        __hip_atomic_store((unsigned*)hx + (size_t)b * H_ + h, __float_as_uint(h3),
                           __ATOMIC_RELAXED, __HIP_MEMORY_SCOPE_AGENT);

        // (b) group barrier. syncthreads drains each wave's vmcnt (h3 at
        // coherence point); RELEASE on the flag orders it after the data.
        __syncthreads();
        const unsigned gen = (unsigned)(t + 1);
        if (tid == 0)
            __hip_atomic_store(&flags[g], gen, __ATOMIC_RELEASE,
                               __HIP_MEMORY_SCOPE_AGENT);

        // prefetch next step's xw while waiting (row owned by this thread)
        xwv = out[rowoff + H_ + h];

        if (tid < 32) {
            const unsigned* f = &flags[p + 8 * tid];
            // '<' not '!=': a fast group member may advance its flag past
            // gen before we poll. flags memset to 0 on stream each launch.
            while (__hip_atomic_load(f, __ATOMIC_ACQUIRE,
                                     __HIP_MEMORY_SCOPE_AGENT) < gen) {}
        }
        __syncthreads();

        // (c) stage this group's h3 slice (8 batches x 1024) into Hl.
        {
            const ull* hxp = (const ull*)(hx + (size_t)p * 8 * H_);
            ull hv[16];
#pragma unroll
            for (int j = 0; j < 16; ++j)
                hv[j] = aload(hxp + tid + 256 * j);
#pragma unroll
            for (int j = 0; j < 16; ++j) {
                int f = tid + 256 * j;
                *(ull*)&Hl[f >> 9][(f & 511) * 2] = hv[j];
            }
        }
        __syncthreads();

        // (d) GEMV from LDS — r1-identical order: k = m*32 + 2kq + {0,1}
        float acc[4][4] = {};
#pragma unroll
        for (int m = 0; m < 32; ++m) {
            const int ko = m * 32 + hbase;
            float2 hh0 = *(const float2*)&Hl[lb0 + 0][ko];
            float2 hh1 = *(const float2*)&Hl[lb0 + 1][ko];
            float2 hh2 = *(const float2*)&Hl[lb0 + 2][ko];
            float2 hh3 = *(const float2*)&Hl[lb0 + 3][ko];
#pragma unroll
            for (int c = 0; c < 4; ++c) {
                const float2 uu =
                    *(const float2*)&Ul[rowc[c]][(uo[c] + m * 32) & 1023];
                acc[0][c] += hh0.x * uu.x + hh0.y * uu.y;
                acc[1][c] += hh1.x * uu.x + hh1.y * uu.y;
                acc[2][c] += hh2.x * uu.x + hh2.y * uu.y;
                acc[3][c] += hh3.x * uu.x + hh3.y * uu.y;
            }
        }

        // 16-way k-reduction over the kq lane bits
#pragma unroll
        for (int i = 0; i < 4; ++i)
#pragma unroll
            for (int c = 0; c < 4; ++c) {
                float v = acc[i][c];
                v += __shfl_xor(v, 1);
                v += __shfl_xor(v, 2);
                v += __shfl_xor(v, 4);
                v += __shfl_xor(v, 8);
                acc[i][c] = v;
            }

        // select this thread's (b,h): i = kq>>2, c = kq&3
        float r = acc[0][0];
#pragma unroll
        for (int i = 0; i < 4; ++i)
#pragma unroll
            for (int c = 0; c < 4; ++c)
                if (((kq >> 2) == i) && ((kq & 3) == c)) r = acc[i][c];

        s = bUh + r;
    }
}

// ---------------------------------------------------------------------------
extern "C" void kernel_launch(void* const* d_in, const int* in_sizes, int n_in,
                              void* d_out, int out_size, void* d_ws, size_t ws_size,
                              hipStream_t stream) {
    const float* x  = (const float*)d_in[0];
    const float* W  = (const float*)d_in[1];
    const float* bW = (const float*)d_in[2];
    const float* U  = (const float*)d_in[3];
    const float* bU = (const float*)d_in[4];
    float* out = (float*)d_out;

    float* hx0 = (float*)d_ws;
    float* hx1 = hx0 + (size_t)B_ * H_;
    unsigned* flags = (unsigned*)(hx1 + (size_t)B_ * H_);

    // flags must start below gen=1 for the '<' spin; don't trust ws contents
    hipMemsetAsync(flags, 0, 256 * sizeof(unsigned), stream);

    dim3 g1(H_ / TS, (B_ * T_) / TS);
    gemm_xw<<<g1, dim3(256), 0, stream>>>(x, W, bW, out);

    void* args[] = {(void*)&U, (void*)&bU, (void*)&out,
                    (void*)&hx0, (void*)&hx1, (void*)&flags};
    hipLaunchCooperativeKernel((void*)rnn_scan, dim3(256), dim3(256), args, 0,
                               stream);
}

// Round 4
// 4822.923 us; speedup vs baseline: 2.0566x; 2.0566x over previous
//
#include <hip/hip_runtime.h>
#include <cmath>

#define B_ 64
#define T_ 512
#define I_ 1024
#define H_ 1024

// ---------------------------------------------------------------------------
// Kernel 1: xw[m, n] = sum_k x[m,k] * W[n,k] + bW[n]   (M=32768, N=1024, K=1024)
// Written into the out1 region of d_out. 128x128 tile, BK=8, 8x8 per thread.
// (unchanged from verified baseline)
// ---------------------------------------------------------------------------
#define TS 128
#define KS 8

__global__ __launch_bounds__(256) void gemm_xw(const float* __restrict__ x,
                                               const float* __restrict__ W,
                                               const float* __restrict__ bW,
                                               float* __restrict__ out) {
    __shared__ float As[KS][TS];
    __shared__ float Bs[KS][TS];

    const int tid = threadIdx.x;
    const int tx = tid & 15;
    const int ty = tid >> 4;
    const int m0 = blockIdx.y * TS;
    const int n0 = blockIdx.x * TS;

    const int lr = tid >> 1;
    const int lk = (tid & 1) * 4;

    const float* xa = x + (size_t)(m0 + lr) * I_ + lk;
    const float* wb = W + (size_t)(n0 + lr) * I_ + lk;

    float acc[8][8] = {};

    for (int k0 = 0; k0 < I_; k0 += KS) {
        float4 a = *(const float4*)(xa + k0);
        float4 bv = *(const float4*)(wb + k0);
        __syncthreads();
        As[lk + 0][lr] = a.x;  As[lk + 1][lr] = a.y;
        As[lk + 2][lr] = a.z;  As[lk + 3][lr] = a.w;
        Bs[lk + 0][lr] = bv.x; Bs[lk + 1][lr] = bv.y;
        Bs[lk + 2][lr] = bv.z; Bs[lk + 3][lr] = bv.w;
        __syncthreads();
#pragma unroll
        for (int kk = 0; kk < KS; ++kk) {
            float av[8], bw8[8];
            *(float4*)&av[0]  = *(const float4*)&As[kk][ty * 8];
            *(float4*)&av[4]  = *(const float4*)&As[kk][ty * 8 + 4];
            *(float4*)&bw8[0] = *(const float4*)&Bs[kk][tx * 8];
            *(float4*)&bw8[4] = *(const float4*)&Bs[kk][tx * 8 + 4];
#pragma unroll
            for (int i = 0; i < 8; ++i)
#pragma unroll
                for (int j = 0; j < 8; ++j)
                    acc[i][j] += av[i] * bw8[j];
        }
    }

    float bias[8];
    *(float4*)&bias[0] = *(const float4*)&bW[n0 + tx * 8];
    *(float4*)&bias[4] = *(const float4*)&bW[n0 + tx * 8 + 4];
#pragma unroll
    for (int i = 0; i < 8; ++i) {
        float* o = out + (size_t)(m0 + ty * 8 + i) * H_ + n0 + tx * 8;
        float4 v0, v1;
        v0.x = acc[i][0] + bias[0]; v0.y = acc[i][1] + bias[1];
        v0.z = acc[i][2] + bias[2]; v0.w = acc[i][3] + bias[3];
        v1.x = acc[i][4] + bias[4]; v1.y = acc[i][5] + bias[5];
        v1.z = acc[i][6] + bias[6]; v1.w = acc[i][7] + bias[7];
        *(float4*)(o)     = v0;
        *(float4*)(o + 4) = v1;
    }
}

// ---------------------------------------------------------------------------
// Kernel 2: persistent recurrence, batch-grouped, LDS-staged h3.
// 256 WGs x 256 threads. WG g: p = g&7 (batches 8p..8p+8), q = g>>3
// (cols 32q..32q+32). U slice (32x1024, rotation-swizzled) + h3 slice
// (8x1024) resident in LDS = exactly 160 KiB.
//
// Flags are RELAXED on both sides (r1-proven). Do NOT use acquire/release
// here: agent-scope release emits buffer_wbl2 sc1 and each acquire load
// emits buffer_inv sc1 -> whole-L2 writeback/invalidate inside the spin
// loop. r3 measured the cost: WRITE_SIZE 266->888 MB, VALUBusy 40->16%,
// 2x step time. Ordering is already guaranteed: __syncthreads() drains
// vmcnt, so hx atomic stores complete at MALL before the flag store.
//
// Per step: group-local flag barrier (32 flags, '<' spin); then each WG
// stages its 32 KB h3 slice global->LDS ONCE (relaxed agent atomic
// loads), GEMV entirely from LDS (8 MB/step L3 traffic vs r1's 64).
//
// GEMV arithmetic is ORDER-IDENTICAL to the verified r1/r3 kernels
// (float2 granule, k = m*32 + 2kq + {0,1}, m = 0..31 ascending, same
// accumulate expression, same shfl_xor butterfly) -> 1-ulp absmax.
// Recurrence is drift-sensitive; do not reassociate the k-sum.
//
// Thread map: tile = tid>>4 (bt = tile&1 batch-half, ct = tile>>1 col),
// kq = tid&15. bt varies INSIDE a wave -> U reads are 2-way broadcast.
// U rotation Ul[r][(k+4r)&1023] kills row-stride bank aliasing
// (SQ_LDS_BANK_CONFLICT == 0 measured in r3).
// Owner: b = 8p + 4bt + (kq>>2), h = 32q + ct + 8*(kq&3)  (bijective).
// ---------------------------------------------------------------------------
typedef unsigned long long ull;

__device__ __forceinline__ ull aload(const ull* p) {
    return __hip_atomic_load(p, __ATOMIC_RELAXED, __HIP_MEMORY_SCOPE_AGENT);
}
__device__ __forceinline__ unsigned aload32(const unsigned* p) {
    return __hip_atomic_load(p, __ATOMIC_RELAXED, __HIP_MEMORY_SCOPE_AGENT);
}

__global__ __launch_bounds__(256) void rnn_scan(const float* __restrict__ U,
                                                const float* __restrict__ bU,
                                                float* __restrict__ out,
                                                float* __restrict__ hx0,
                                                float* __restrict__ hx1,
                                                unsigned* __restrict__ flags) {
    __shared__ __align__(16) float Ul[32][1024];   // 131072 B (rot-swizzled)
    __shared__ __align__(16) float Hl[8][1024];    //  32768 B

    const int g = blockIdx.x;
    const int p = g & 7;          // batch group
    const int q = g >> 3;         // col group
    const int tid = threadIdx.x;

    const int tile = tid >> 4;    // 0..15
    const int kq = tid & 15;      // 0..15
    const int bt = tile & 1;      // batch half (varies within wave)
    const int ct = tile >> 1;     // 0..7 col index

    // owner identity: bijective over tid
    const int b = p * 8 + bt * 4 + (kq >> 2);
    const int h = q * 32 + ct + 8 * (kq & 3);

    // --- stage U rows [32q, 32q+32) into LDS, rotation swizzle ---
    // U[q*32+r][k]  ->  Ul[r][(k + 4r) & 1023]
    {
        const float* Ubase = U + (size_t)q * 32 * H_;
#pragma unroll 4
        for (int it = 0; it < 32; ++it) {
            int f4 = it * 256 + tid;        // float4 index, coalesced
            int r = f4 >> 8;                // 256 float4 per row
            int k = (f4 & 255) * 4;
            float4 v = *(const float4*)(Ubase + (size_t)r * H_ + k);
            int kd = (k + 4 * r) & 1023;
            *(float4*)&Ul[r][kd] = v;
        }
    }
    __syncthreads();

    const float bUh = bU[h];
    float s = 0.0f;
    float* out2 = out + (size_t)B_ * T_ * H_;

    const int lb0 = bt * 4;                 // local batch base in Hl
    // per-thread U row indices + rotated base offsets (k = m*32 + 2kq)
    int rowc[4], uo[4];
#pragma unroll
    for (int c = 0; c < 4; ++c) {
        rowc[c] = ct + 8 * c;
        uo[c] = (4 * rowc[c] + 2 * kq) & 1023;
    }
    const int hbase = 2 * kq;

    float xwv = out[(size_t)b * T_ * H_ + h];   // xw for t=0

    for (int t = 0; t < T_; ++t) {
        // (a) elementwise: h3 = tanh(xw + s); out1 in place
        const size_t rowoff = ((size_t)b * T_ + t) * H_;
        float h3 = tanhf(xwv + s);
        out[rowoff + h] = h3;
        if (t == T_ - 1) {
            out2[(size_t)b * H_ + h] = h3;
            break;
        }

        float* hx = (t & 1) ? hx1 : hx0;
        __hip_atomic_store((unsigned*)hx + (size_t)b * H_ + h, __float_as_uint(h3),
                           __ATOMIC_RELAXED, __HIP_MEMORY_SCOPE_AGENT);

        // (b) group barrier: syncthreads drains vmcnt (h3 stores complete
        // at MALL), then raise own flag; all-gather the 32 group flags.
        __syncthreads();
        const unsigned gen = (unsigned)(t + 1);
        if (tid == 0)
            __hip_atomic_store(&flags[g], gen, __ATOMIC_RELAXED,
                               __HIP_MEMORY_SCOPE_AGENT);

        // prefetch next step's xw while waiting (row owned by this thread)
        xwv = out[rowoff + H_ + h];

        if (tid < 32) {
            const unsigned* f = &flags[p + 8 * tid];
            // '<' not '!=': a fast group member may advance its flag past
            // gen before we poll. flags memset to 0 on stream each launch.
            while (aload32(f) < gen) {}
        }
        __syncthreads();

        // (c) stage this group's h3 slice (8 batches x 1024) into Hl.
        {
            const ull* hxp = (const ull*)(hx + (size_t)p * 8 * H_);
            ull hv[16];
#pragma unroll
            for (int j = 0; j < 16; ++j)
                hv[j] = aload(hxp + tid + 256 * j);
#pragma unroll
            for (int j = 0; j < 16; ++j) {
                int f = tid + 256 * j;
                *(ull*)&Hl[f >> 9][(f & 511) * 2] = hv[j];
            }
        }
        __syncthreads();

        // (d) GEMV from LDS — r1-identical order: k = m*32 + 2kq + {0,1}
        float acc[4][4] = {};
#pragma unroll
        for (int m = 0; m < 32; ++m) {
            const int ko = m * 32 + hbase;
            float2 hh0 = *(const float2*)&Hl[lb0 + 0][ko];
            float2 hh1 = *(const float2*)&Hl[lb0 + 1][ko];
            float2 hh2 = *(const float2*)&Hl[lb0 + 2][ko];
            float2 hh3 = *(const float2*)&Hl[lb0 + 3][ko];
#pragma unroll
            for (int c = 0; c < 4; ++c) {
                const float2 uu =
                    *(const float2*)&Ul[rowc[c]][(uo[c] + m * 32) & 1023];
                acc[0][c] += hh0.x * uu.x + hh0.y * uu.y;
                acc[1][c] += hh1.x * uu.x + hh1.y * uu.y;
                acc[2][c] += hh2.x * uu.x + hh2.y * uu.y;
                acc[3][c] += hh3.x * uu.x + hh3.y * uu.y;
            }
        }

        // 16-way k-reduction over the kq lane bits
#pragma unroll
        for (int i = 0; i < 4; ++i)
#pragma unroll
            for (int c = 0; c < 4; ++c) {
                float v = acc[i][c];
                v += __shfl_xor(v, 1);
                v += __shfl_xor(v, 2);
                v += __shfl_xor(v, 4);
                v += __shfl_xor(v, 8);
                acc[i][c] = v;
            }

        // select this thread's (b,h): i = kq>>2, c = kq&3
        float r = acc[0][0];
#pragma unroll
        for (int i = 0; i < 4; ++i)
#pragma unroll
            for (int c = 0; c < 4; ++c)
                if (((kq >> 2) == i) && ((kq & 3) == c)) r = acc[i][c];

        s = bUh + r;
    }
}

// ---------------------------------------------------------------------------
extern "C" void kernel_launch(void* const* d_in, const int* in_sizes, int n_in,
                              void* d_out, int out_size, void* d_ws, size_t ws_size,
                              hipStream_t stream) {
    const float* x  = (const float*)d_in[0];
    const float* W  = (const float*)d_in[1];
    const float* bW = (const float*)d_in[2];
    const float* U  = (const float*)d_in[3];
    const float* bU = (const float*)d_in[4];
    float* out = (float*)d_out;

    float* hx0 = (float*)d_ws;
    float* hx1 = hx0 + (size_t)B_ * H_;
    unsigned* flags = (unsigned*)(hx1 + (size_t)B_ * H_);

    // flags must start below gen=1 for the '<' spin; don't trust ws contents
    hipMemsetAsync(flags, 0, 256 * sizeof(unsigned), stream);

    dim3 g1(H_ / TS, (B_ * T_) / TS);
    gemm_xw<<<g1, dim3(256), 0, stream>>>(x, W, bW, out);

    void* args[] = {(void*)&U, (void*)&bU, (void*)&out,
                    (void*)&hx0, (void*)&hx1, (void*)&flags};
    hipLaunchCooperativeKernel((void*)rnn_scan, dim3(256), dim3(256), args, 0,
                               stream);
}

// Round 7
// 3807.984 us; speedup vs baseline: 2.6048x; 1.2665x over previous
//
#include <hip/hip_runtime.h>
#include <cmath>

#define B_ 64
#define T_ 512
#define I_ 1024
#define H_ 1024

// ---------------------------------------------------------------------------
// Kernel 1: xw[m, n] = sum_k x[m,k] * W[n,k] + bW[n]   (M=32768, N=1024, K=1024)
// Written into the out1 region of d_out. 128x128 tile, BK=8, 8x8 per thread.
// (unchanged from verified baseline)
// ---------------------------------------------------------------------------
#define TS 128
#define KS 8

__global__ __launch_bounds__(256) void gemm_xw(const float* __restrict__ x,
                                               const float* __restrict__ W,
                                               const float* __restrict__ bW,
                                               float* __restrict__ out) {
    __shared__ float As[KS][TS];
    __shared__ float Bs[KS][TS];

    const int tid = threadIdx.x;
    const int tx = tid & 15;
    const int ty = tid >> 4;
    const int m0 = blockIdx.y * TS;
    const int n0 = blockIdx.x * TS;

    const int lr = tid >> 1;
    const int lk = (tid & 1) * 4;

    const float* xa = x + (size_t)(m0 + lr) * I_ + lk;
    const float* wb = W + (size_t)(n0 + lr) * I_ + lk;

    float acc[8][8] = {};

    for (int k0 = 0; k0 < I_; k0 += KS) {
        float4 a = *(const float4*)(xa + k0);
        float4 bv = *(const float4*)(wb + k0);
        __syncthreads();
        As[lk + 0][lr] = a.x;  As[lk + 1][lr] = a.y;
        As[lk + 2][lr] = a.z;  As[lk + 3][lr] = a.w;
        Bs[lk + 0][lr] = bv.x; Bs[lk + 1][lr] = bv.y;
        Bs[lk + 2][lr] = bv.z; Bs[lk + 3][lr] = bv.w;
        __syncthreads();
#pragma unroll
        for (int kk = 0; kk < KS; ++kk) {
            float av[8], bw8[8];
            *(float4*)&av[0]  = *(const float4*)&As[kk][ty * 8];
            *(float4*)&av[4]  = *(const float4*)&As[kk][ty * 8 + 4];
            *(float4*)&bw8[0] = *(const float4*)&Bs[kk][tx * 8];
            *(float4*)&bw8[4] = *(const float4*)&Bs[kk][tx * 8 + 4];
#pragma unroll
            for (int i = 0; i < 8; ++i)
#pragma unroll
                for (int j = 0; j < 8; ++j)
                    acc[i][j] += av[i] * bw8[j];
        }
    }

    float bias[8];
    *(float4*)&bias[0] = *(const float4*)&bW[n0 + tx * 8];
    *(float4*)&bias[4] = *(const float4*)&bW[n0 + tx * 8 + 4];
#pragma unroll
    for (int i = 0; i < 8; ++i) {
        float* o = out + (size_t)(m0 + ty * 8 + i) * H_ + n0 + tx * 8;
        float4 v0, v1;
        v0.x = acc[i][0] + bias[0]; v0.y = acc[i][1] + bias[1];
        v0.z = acc[i][2] + bias[2]; v0.w = acc[i][3] + bias[3];
        v1.x = acc[i][4] + bias[4]; v1.y = acc[i][5] + bias[5];
        v1.z = acc[i][6] + bias[6]; v1.w = acc[i][7] + bias[7];
        *(float4*)(o)     = v0;
        *(float4*)(o + 4) = v1;
    }
}

// ---------------------------------------------------------------------------
// Kernel 2: persistent recurrence, U-in-registers, 512-thread WGs.
//
// r6 post-mortem: absmax 2.18 > 2 proves rnn_scan NEVER RAN (tanh output
// is bounded by 1; out1 still held raw xw). The 512-block cooperative
// launch (2 WGs/CU) was rejected by the driver's occupancy check and the
// ignored error made it a silent no-op. Fix: keep the r4-PROVEN launch
// shape (256 blocks, 1 WG/CU, cooperative) and get 2 waves/SIMD via
// 512-thread workgroups (8 waves/CU) instead of 2 WGs/CU.
//
// r4 post-mortem (still the driving theory): the scan is LATENCY-bound —
// 160 KiB LDS forced 1 wave/SIMD (Occupancy 11.6%), so MALL-barrier,
// staging, and LDS latencies all serialized. Here U lives in VGPRs
// (each thread: 2 cols x 32 float2 = 128 regs, loaded once), LDS holds
// only the 8-batch h3 slice (32 KiB) -> 2 waves/SIMD co-schedule.
//
// Partition (r4 shape): WG g: p = g&7 (batches 8p..8p+8), q = g>>3
// (cols 32q..32q+32). Thread tid<512: kq = tid&15, ctile = (tid>>4)&15,
// bt = tid>>8. GEMV: 4 batches (bt*4..+4 local) x 2 cols
// {32q + 2*ctile + c}, k = m*32 + 2kq + {0,1}. bt is wave-uniform;
// Hl reads are 4-way broadcast (ctile in-wave) -> conflict-free.
//
// BIT-EXACTNESS (r2 lesson: the recurrence amplifies reassociation):
// per-output k-chain is IDENTICAL to verified r4: same k-slice per kq
// lane, ascending m, float2 granule, same accumulate expression, same
// 4-step shfl_xor butterfly. Only operand SOURCE changes (U: LDS->regs).
//
// Owner map (kq<8): b = 8p + bt*4 + (kq>>1), h = 32q + 2*ctile + (kq&1)
// — bijective over the grid (256 owners/WG = 8 batches x 32 cols).
// kq>=8 lanes assist staging/GEMV/butterfly but never store.
//
// Flags RELAXED both sides (r3 measured acq/rel cost: whole-L2
// writeback/invalidate in the spin, 2x step time). __syncthreads()
// drains vmcnt so hx stores complete at MALL before the flag store.
// Spin pattern is r4's proven flags[tid*8 + p], '<' comparison.
// ---------------------------------------------------------------------------
typedef unsigned long long ull;

__device__ __forceinline__ ull aload(const ull* p) {
    return __hip_atomic_load(p, __ATOMIC_RELAXED, __HIP_MEMORY_SCOPE_AGENT);
}
__device__ __forceinline__ unsigned aload32(const unsigned* p) {
    return __hip_atomic_load(p, __ATOMIC_RELAXED, __HIP_MEMORY_SCOPE_AGENT);
}

__global__ __launch_bounds__(512, 2) void rnn_scan(const float* __restrict__ U,
                                                   const float* __restrict__ bU,
                                                   float* __restrict__ out,
                                                   float* __restrict__ hx0,
                                                   float* __restrict__ hx1,
                                                   unsigned* __restrict__ flags) {
    __shared__ __align__(16) float Hl[8][1024];   // 32 KiB

    const int g = blockIdx.x;
    const int p = g & 7;          // batch group (8 batches)
    const int q = g >> 3;         // col group (32 cols)
    const int tid = threadIdx.x;  // 0..511

    const int kq = tid & 15;         // k-slice lane
    const int ctile = (tid >> 4) & 15;  // col pair
    const int bt = tid >> 8;         // batch half (wave-uniform)

    // owner identity (valid for kq < 8; addresses in-range for all)
    const int b = p * 8 + bt * 4 + ((kq & 7) >> 1);
    const int h = q * 32 + ctile * 2 + (kq & 1);
    const bool owner = (kq < 8);

    // --- load this thread's U slice into registers (one-time) ---
    // cols 32q + 2*ctile + {0,1}; k = m*32 + 2*kq + {0,1}
    const float* Uc0 = U + (size_t)(q * 32 + ctile * 2) * H_ + 2 * kq;
    const float* Uc1 = Uc0 + H_;
    float2 u0[32], u1[32];
#pragma unroll
    for (int m = 0; m < 32; ++m) {
        u0[m] = *(const float2*)(Uc0 + m * 32);
        u1[m] = *(const float2*)(Uc1 + m * 32);
    }

    const float bUh = bU[h];
    float s = 0.0f;
    float* out2 = out + (size_t)B_ * T_ * H_;
    const int lb0 = bt * 4;       // local batch base in Hl

    float xwv = owner ? out[(size_t)b * T_ * H_ + h] : 0.0f;

    for (int t = 0; t < T_; ++t) {
        const size_t rowoff = ((size_t)b * T_ + t) * H_;
        float* hx = (t & 1) ? hx1 : hx0;

        if (owner) {
            float h3 = tanhf(xwv + s);
            out[rowoff + h] = h3;
            if (t == T_ - 1) {
                out2[(size_t)b * H_ + h] = h3;
            } else {
                __hip_atomic_store((unsigned*)hx + (size_t)b * H_ + h,
                                   __float_as_uint(h3),
                                   __ATOMIC_RELAXED, __HIP_MEMORY_SCOPE_AGENT);
            }
        }
        if (t == T_ - 1) break;

        // (b) group barrier: syncthreads drains vmcnt (hx stores complete
        // at MALL), then raise own flag; all-gather the 32 group flags.
        __syncthreads();
        const unsigned gen = (unsigned)(t + 1);
        if (tid == 0)
            __hip_atomic_store(&flags[g], gen, __ATOMIC_RELAXED,
                               __HIP_MEMORY_SCOPE_AGENT);

        // prefetch next step's xw while waiting (row owned by this thread)
        if (owner) xwv = out[rowoff + H_ + h];

        if (tid < 32) {
            const unsigned* f = &flags[tid * 8 + p];
            // '<' not '!=': a fast group member may advance its flag past
            // gen before we poll. flags memset to 0 on stream each launch.
            while (aload32(f) < gen) {}
        }
        __syncthreads();

        // (c) stage this group's h3 slice (8 batches x 1024) into Hl.
        {
            const ull* hxp = (const ull*)hx + (size_t)p * 4096;
            ull hv[8];
#pragma unroll
            for (int j = 0; j < 8; ++j)
                hv[j] = aload(hxp + tid + 512 * j);
#pragma unroll
            for (int j = 0; j < 8; ++j) {
                int f = tid + 512 * j;
                *(ull*)&Hl[f >> 9][(f & 511) * 2] = hv[j];
            }
        }
        __syncthreads();

        // (d) GEMV: Hl (4-way broadcast) x U-regs. r4-identical k-order:
        // k = m*32 + 2kq + {0,1}, ascending m, float2 granule.
        float acc[4][2] = {};
#pragma unroll
        for (int m = 0; m < 32; ++m) {
            const int ko = m * 32 + 2 * kq;
            float2 h0 = *(const float2*)&Hl[lb0 + 0][ko];
            float2 h1 = *(const float2*)&Hl[lb0 + 1][ko];
            float2 h2 = *(const float2*)&Hl[lb0 + 2][ko];
            float2 h3v = *(const float2*)&Hl[lb0 + 3][ko];
            acc[0][0] += h0.x * u0[m].x + h0.y * u0[m].y;
            acc[1][0] += h1.x * u0[m].x + h1.y * u0[m].y;
            acc[2][0] += h2.x * u0[m].x + h2.y * u0[m].y;
            acc[3][0] += h3v.x * u0[m].x + h3v.y * u0[m].y;
            acc[0][1] += h0.x * u1[m].x + h0.y * u1[m].y;
            acc[1][1] += h1.x * u1[m].x + h1.y * u1[m].y;
            acc[2][1] += h2.x * u1[m].x + h2.y * u1[m].y;
            acc[3][1] += h3v.x * u1[m].x + h3v.y * u1[m].y;
        }

        // 16-way k-reduction over the kq lane bits (identical to r4)
#pragma unroll
        for (int i = 0; i < 4; ++i)
#pragma unroll
            for (int c = 0; c < 2; ++c) {
                float v = acc[i][c];
                v += __shfl_xor(v, 1);
                v += __shfl_xor(v, 2);
                v += __shfl_xor(v, 4);
                v += __shfl_xor(v, 8);
                acc[i][c] = v;
            }

        // owner lane (kq<8) selects its (b,h): i = kq>>1, c = kq&1
        float r = acc[0][0];
#pragma unroll
        for (int i = 0; i < 4; ++i)
#pragma unroll
            for (int c = 0; c < 2; ++c)
                if ((((kq & 7) >> 1) == i) && ((kq & 1) == c)) r = acc[i][c];

        s = bUh + r;
    }
}

// ---------------------------------------------------------------------------
extern "C" void kernel_launch(void* const* d_in, const int* in_sizes, int n_in,
                              void* d_out, int out_size, void* d_ws, size_t ws_size,
                              hipStream_t stream) {
    const float* x  = (const float*)d_in[0];
    const float* W  = (const float*)d_in[1];
    const float* bW = (const float*)d_in[2];
    const float* U  = (const float*)d_in[3];
    const float* bU = (const float*)d_in[4];
    float* out = (float*)d_out;

    float* hx0 = (float*)d_ws;
    float* hx1 = hx0 + (size_t)B_ * H_;
    unsigned* flags = (unsigned*)(hx1 + (size_t)B_ * H_);

    // flags must start below gen=1 for the '<' spin; don't trust ws contents
    hipMemsetAsync(flags, 0, 256 * sizeof(unsigned), stream);

    dim3 g1(H_ / TS, (B_ * T_) / TS);
    gemm_xw<<<g1, dim3(256), 0, stream>>>(x, W, bW, out);

    void* args[] = {(void*)&U, (void*)&bU, (void*)&out,
                    (void*)&hx0, (void*)&hx1, (void*)&flags};
    hipLaunchCooperativeKernel((void*)rnn_scan, dim3(256), dim3(512), args, 0,
                               stream);
}